// Round 2
// baseline (235.425 us; speedup 1.0000x reference)
//
#include <hip/hip_runtime.h>
#include <math.h>

// Problem constants (from reference): features [B,H,W,D,F] float32
#define BB 16
#define HH 128
#define WW 128
#define DD 8
#define FF 16

// Fused: rotate(40deg, NN, expand=False, fill=0) -> roll((5,-7),(H,W)) -> flip(W,D)
// out[b,h,w,d,f] = valid(i,j) ? feat[b, si(i,j), sj(i,j), 7-d, f] : 0
//   i = (h - 5) mod H ; j = (134 - w) mod W
//
// v2: one thread = (h,w,d,f4), loops over all 16 b.
//  - rotation map (f64, exact rint half-to-even) computed ONCE per thread
//    instead of 32x redundantly across (d,f4) and 16x across b
//  - 16 independent load/store pairs per thread -> deep memory-level
//    parallelism; b-stride is a uniform 8 MiB offset so per-instruction
//    wave coalescing (4 lanes x 16B = contiguous 64B) is unchanged
//  - non-temporal stores: output is write-once, keep it out of L2/L3 so
//    the input gather's reuse (NN duplicates, diagonal line sharing) stays cached
//  - native clang vector type for the NT builtin (HIP float4 class is rejected)

typedef float floatx4 __attribute__((ext_vector_type(4)));

__global__ __launch_bounds__(256) void aug_kernel(const floatx4* __restrict__ in,
                                                  floatx4* __restrict__ out) {
    int t = blockIdx.x * blockDim.x + threadIdx.x;  // (h,w,d,f4), b looped
    int f4 = t & 3;   t >>= 2;
    int d  = t & 7;   t >>= 3;
    int w  = t & 127; t >>= 7;
    int h  = t;       // 0..127  (grid sized exactly: 128*128*8*4 threads)

    // compose roll + W-flip into rotated-space coords
    int i = (h + 123) & 127;   // (h - 5) mod 128
    int j = (134 - w) & 127;

    // inverse-rotation NN map (f64, exact; rint = half-to-even, matches np.round)
    const double c = 0.76604444311897803;  // cos(40 deg)
    const double s = 0.64278760968653933;  // sin(40 deg)
    const double cy = 63.5, cx = 63.5;
    double di = (double)i - cy;
    double dj = (double)j - cx;
    int si = (int)rint(c * di + s * dj + cy);
    int sj = (int)rint(-s * di + c * dj + cx);
    bool valid = (si >= 0) & (si < HH) & (sj >= 0) & (sj < WW);

    const int STRIDE = HH * WW * DD * (FF / 4);      // float4 per batch = 524288
    int out0 = ((h * WW + w) * DD + d) * 4 + f4;     // b = 0 output index (float4)

    if (valid) {
        int dd = 7 - d;                              // D-flip
        int src0 = ((si * WW + sj) * DD + dd) * 4 + f4;
        #pragma unroll
        for (int b = 0; b < BB; ++b) {
            floatx4 v = in[src0 + b * STRIDE];
            __builtin_nontemporal_store(v, &out[out0 + b * STRIDE]);
        }
    } else {
        floatx4 z = (floatx4)(0.f);
        #pragma unroll
        for (int b = 0; b < BB; ++b) {
            __builtin_nontemporal_store(z, &out[out0 + b * STRIDE]);
        }
    }
}

extern "C" void kernel_launch(void* const* d_in, const int* in_sizes, int n_in,
                              void* d_out, int out_size, void* d_ws, size_t ws_size,
                              hipStream_t stream) {
    const floatx4* in = (const floatx4*)d_in[0];
    floatx4* out = (floatx4*)d_out;
    int n_threads = HH * WW * DD * (FF / 4);  // 524288 (b handled in-thread)
    int block = 256;
    int grid = n_threads / block;             // 2048, exact
    aug_kernel<<<grid, block, 0, stream>>>(in, out);
}

// Round 3
// 231.935 us; speedup vs baseline: 1.0150x; 1.0150x over previous
//
#include <hip/hip_runtime.h>
#include <math.h>

// Problem constants (from reference): features [B,H,W,D,F] float32
#define BB 16
#define HH 128
#define WW 128
#define DD 8
#define FF 16

// Fused: rotate(40deg, NN, expand=False, fill=0) -> roll((5,-7),(H,W)) -> flip(W,D)
// out[b,h,w,d,f] = valid(i,j) ? feat[b, si(i,j), sj(i,j), 7-d, f] : 0
//   i = (h - 5) mod H ; j = (134 - w) mod W
//
// v3: one thread = (b,h,w,f4), unrolled loop over d (8 iters).
//  - b stays OUTERMOST in the grid (v2's b-loop thrashed L2 across 16 batches
//    -> regression; per-batch 8 MiB input slice is cache-resident)
//  - the 8 source elements (si,sj,7-d,f4) span one contiguous 512B block:
//    8 loads off one base with immediate offsets, 8-deep MLP per thread,
//    map computed once per thread instead of 8x
//  - stores: d and d+1 halves of each 128B line written back-to-back by the
//    same wave -> L2 merges to full-line writebacks
//  - plain stores (NT reverted - confounded in v2's regression)

typedef float floatx4 __attribute__((ext_vector_type(4)));

__global__ __launch_bounds__(256) void aug_kernel(const floatx4* __restrict__ in,
                                                  floatx4* __restrict__ out) {
    int t = blockIdx.x * blockDim.x + threadIdx.x;  // (b,h,w,f4), d looped
    int f4 = t & 3;
    int w  = (t >> 2) & 127;
    int h  = (t >> 9) & 127;
    int b  = t >> 16;          // 0..15

    // compose roll + W-flip into rotated-space coords
    int i = (h + 123) & 127;   // (h - 5) mod 128
    int j = (134 - w) & 127;

    // inverse-rotation NN map (f64, exact; rint = half-to-even, matches np.round)
    const double c = 0.76604444311897803;  // cos(40 deg)
    const double s = 0.64278760968653933;  // sin(40 deg)
    const double cy = 63.5, cx = 63.5;
    double di = (double)i - cy;
    double dj = (double)j - cx;
    int si = (int)rint(c * di + s * dj + cy);
    int sj = (int)rint(-s * di + c * dj + cx);
    bool valid = (si >= 0) & (si < HH) & (sj >= 0) & (sj < WW);

    // float4 index of (b,h,w,d=0,f4): features are 4 float4 per (b,h,w,d)
    int out0 = (((b * HH + h) * WW + w) * DD) * 4 + f4;

    if (valid) {
        int src0 = (((b * HH + si) * WW + sj) * DD) * 4 + f4;
        #pragma unroll
        for (int d = 0; d < DD; ++d) {
            floatx4 v = in[src0 + (7 - d) * 4];   // D-flip: dd = 7-d
            out[out0 + d * 4] = v;
        }
    } else {
        floatx4 z = (floatx4)(0.f);
        #pragma unroll
        for (int d = 0; d < DD; ++d) {
            out[out0 + d * 4] = z;
        }
    }
}

extern "C" void kernel_launch(void* const* d_in, const int* in_sizes, int n_in,
                              void* d_out, int out_size, void* d_ws, size_t ws_size,
                              hipStream_t stream) {
    const floatx4* in = (const floatx4*)d_in[0];
    floatx4* out = (floatx4*)d_out;
    int n_threads = BB * HH * WW * (FF / 4);  // 1,048,576 (d handled in-thread)
    int block = 256;
    int grid = n_threads / block;             // 4096, exact
    aug_kernel<<<grid, block, 0, stream>>>(in, out);
}

// Round 4
// 224.161 us; speedup vs baseline: 1.0502x; 1.0347x over previous
//
#include <hip/hip_runtime.h>
#include <math.h>

// Problem constants (from reference): features [B,H,W,D,F] float32
#define BB 16
#define HH 128
#define WW 128
#define DD 8
#define FF 16

// Fused: rotate(40deg, NN, expand=False, fill=0) -> roll((5,-7),(H,W)) -> flip(W,D)
// out[b,h,w,d,f] = valid(i,j) ? feat[b, si(i,j), sj(i,j), 7-d, f] : 0
//   i = (h - 5) mod H ; j = (134 - w) mod W
//
// v4 = v1 (best verified structure: 1 thread : 1 output float4, linear tid)
//      + XCD-aware chunked blockIdx swizzle (T1): each XCD owns a contiguous
//        1/8 of output space so adjacent-h source-row overlap (NN duplicates,
//        shared 128B lines) is absorbed by its own L2 instead of re-fetched
//        from HBM by other XCDs' L2s (non-coherent).
//      + non-temporal stores: output is write-once; keep the 128 MiB store
//        stream from evicting the gather's read window out of L2.
//        (wave stores are full-line contiguous, so NT write-combining is safe)
// v2 (b-loop) and v3 (d-loop) both regressed vs v1 - structure reverted.

typedef float floatx4 __attribute__((ext_vector_type(4)));

__global__ __launch_bounds__(256) void aug_kernel(const floatx4* __restrict__ in,
                                                  floatx4* __restrict__ out) {
    // bijective chunked swizzle: 32768 blocks, 32768 % 8 == 0
    const int NB  = (BB * HH * WW * DD * (FF / 4)) / 256;  // 32768 blocks
    const int CPX = NB / 8;                                 // 4096 per XCD
    int bid = blockIdx.x;
    int sb  = (bid & 7) * CPX + (bid >> 3);   // XCD (bid&7) gets contiguous range
    int tid = sb * 256 + (int)threadIdx.x;    // linear output float4 index

    // decompose: tid = ((((b*H + h)*W + w)*D + d)*4 + f4)
    int t  = tid;
    int f4 = t & 3;   t >>= 2;
    int d  = t & 7;   t >>= 3;
    int w  = t & 127; t >>= 7;
    int h  = t & 127; t >>= 7;
    int b  = t;       // 0..15

    // compose roll + W-flip into rotated-space coords
    int i = (h + 123) & 127;   // (h - 5) mod 128
    int j = (134 - w) & 127;

    // inverse-rotation NN map (f64, exact; rint = half-to-even, matches np.round)
    const double c = 0.76604444311897803;  // cos(40 deg)
    const double s = 0.64278760968653933;  // sin(40 deg)
    const double cy = 63.5, cx = 63.5;
    double di = (double)i - cy;
    double dj = (double)j - cx;
    int si = (int)rint(c * di + s * dj + cy);
    int sj = (int)rint(-s * di + c * dj + cx);
    bool valid = (si >= 0) & (si < HH) & (sj >= 0) & (sj < WW);

    floatx4 v = (floatx4)(0.f);
    if (valid) {
        int dd = 7 - d;  // D-flip
        int src = ((((b * HH) + si) * WW + sj) * DD + dd) * 4 + f4;
        v = in[src];
    }
    __builtin_nontemporal_store(v, &out[tid]);
}

extern "C" void kernel_launch(void* const* d_in, const int* in_sizes, int n_in,
                              void* d_out, int out_size, void* d_ws, size_t ws_size,
                              hipStream_t stream) {
    const floatx4* in = (const floatx4*)d_in[0];
    floatx4* out = (floatx4*)d_out;
    int n_vec4 = out_size / 4;                // 8388608 output float4
    int block = 256;
    int grid = n_vec4 / block;                // 32768, exact
    aug_kernel<<<grid, block, 0, stream>>>(in, out);
}

// Round 5
// 220.841 us; speedup vs baseline: 1.0660x; 1.0150x over previous
//
#include <hip/hip_runtime.h>
#include <math.h>

// Problem constants (from reference): features [B,H,W,D,F] float32
#define BB 16
#define HH 128
#define WW 128
#define DD 8
#define FF 16

// Fused: rotate(40deg, NN, expand=False, fill=0) -> roll((5,-7),(H,W)) -> flip(W,D)
// out[b,h,w,d,f] = valid(i,j) ? feat[b, si(i,j), sj(i,j), 7-d, f] : 0
//   i = (h - 5) mod H ; j = (W-1-w + 7) mod W = (134 - w) mod W
//
// FINAL (v5 = exact revert to v1, the best harness-verified kernel @221.2us):
//   1 thread : 1 output float4, linear tid = output index.
//   Per wave: 1 KiB linear store + 2x contiguous 512B gather reads. This is
//   the measured optimum. Falsified alternatives (each regressed):
//     v2: b-loop amortization (+NT)  -> 235us (batch interleave thrashed L2)
//     v3: d-loop amortization        -> 232us (store linearity broken)
//     v4: XCD chunked swizzle + NT   -> 224us (no cross-XCD re-fetch to save;
//         duplicate gather reads are temporally local, absorbed by L1/L2)
//   Kernel ~54us vs ~46-48us realistic gather floor; bench floor is the two
//   ~83us harness poison fills. Remaining headroom <= ~3% of bench total.

__global__ __launch_bounds__(256) void aug_kernel(const float4* __restrict__ in,
                                                  float4* __restrict__ out,
                                                  int n_vec4) {
    int tid = blockIdx.x * blockDim.x + threadIdx.x;  // one float4 of output
    if (tid >= n_vec4) return;

    // decompose: tid = ((((b*H + h)*W + w)*D + d)*4 + f4)
    int t  = tid;
    int f4 = t & 3;   t >>= 2;
    int d  = t & 7;   t >>= 3;
    int w  = t & 127; t >>= 7;
    int h  = t & 127; t >>= 7;
    int b  = t;       // 0..15

    // compose roll + W-flip into rotated-space coords
    int i = (h + 123) & 127;   // (h - 5) mod 128
    int j = (134 - w) & 127;

    // inverse-rotation NN map (f64, exact; rint = half-to-even, matches np.round)
    const double c = 0.76604444311897803;  // cos(40 deg)
    const double s = 0.64278760968653933;  // sin(40 deg)
    const double cy = 63.5, cx = 63.5;
    double di = (double)i - cy;
    double dj = (double)j - cx;
    double src_i = c * di + s * dj + cy;
    double src_j = -s * di + c * dj + cx;
    int si = (int)rint(src_i);
    int sj = (int)rint(src_j);
    bool valid = (si >= 0) & (si < HH) & (sj >= 0) & (sj < WW);

    float4 v = make_float4(0.f, 0.f, 0.f, 0.f);
    if (valid) {
        int dd = 7 - d;  // D-flip
        // float4-granular source index: F=16 floats = 4 float4 per (b,h,w,d)
        long long src = ((((long long)b * HH + si) * WW + sj) * DD + dd) * 4 + f4;
        v = in[src];
    }
    out[tid] = v;
}

extern "C" void kernel_launch(void* const* d_in, const int* in_sizes, int n_in,
                              void* d_out, int out_size, void* d_ws, size_t ws_size,
                              hipStream_t stream) {
    const float4* in = (const float4*)d_in[0];
    float4* out = (float4*)d_out;
    int n_vec4 = out_size / 4;  // 33554432 / 4 = 8388608
    int block = 256;
    int grid = (n_vec4 + block - 1) / block;  // 32768
    aug_kernel<<<grid, block, 0, stream>>>(in, out, n_vec4);
}